// Round 1
// baseline (224.741 us; speedup 1.0000x reference)
//
#include <hip/hip_runtime.h>
#include <math.h>

#define NTHREADS 256
#define MAXBLOCKS 2048

// Adaptive Wing loss, fused elementwise + partial reduction.
// THETA=0.5, ALPHA=2.1, W=14, E=1.
// Key simplifications (E==1, THETA/E==0.5):
//   expo = 2.1 - y
//   p    = 0.5^expo            = exp2f(-expo)
//   A    = 14 * expo * 2p/(1+p) = 28*expo*p/(1+p)   [since 0.5^(expo-1) = 2p]
//   C    = 0.5*A - 14*log1p(p)
//   loss_large = A*diff - C = A*(diff - 0.5) + 14*log1p(p)
//   loss_small = 14*log1p(diff^expo) = 14*log1p(exp2f(expo*log2f(diff)))
// diff==0 edge: log2f(0)=-inf -> exp2f(-inf)=0 -> log1p(0)=0 (correct limit).

__device__ __forceinline__ float awing_elem(float xv, float yv) {
    const float THETA = 0.5f;
    const float ALPHA = 2.1f;
    const float Wc    = 14.0f;
    float expo = ALPHA - yv;
    float p    = exp2f(-expo);
    float l1pp = log1pf(p);
    float A    = 28.0f * expo * p / (1.0f + p);
    float diff = fabsf(yv - xv);
    float lsml = Wc * log1pf(exp2f(expo * log2f(diff)));
    float llrg = A * (diff - THETA) + Wc * l1pp;
    return (diff < THETA) ? lsml : llrg;
}

__global__ __launch_bounds__(NTHREADS) void awing_partial_kernel(
    const float* __restrict__ inp, const float* __restrict__ tgt,
    float* __restrict__ partial, int n)
{
    const int tid    = blockIdx.x * blockDim.x + threadIdx.x;
    const int stride = gridDim.x * blockDim.x;
    const int n4     = n >> 2;

    const float4* __restrict__ in4 = (const float4*)inp;
    const float4* __restrict__ tg4 = (const float4*)tgt;

    float acc = 0.0f;
    for (int i = tid; i < n4; i += stride) {
        float4 x = in4[i];
        float4 y = tg4[i];
        acc += awing_elem(x.x, y.x);
        acc += awing_elem(x.y, y.y);
        acc += awing_elem(x.z, y.z);
        acc += awing_elem(x.w, y.w);
    }
    // scalar tail (n % 4 != 0)
    for (int i = (n4 << 2) + tid; i < n; i += stride) {
        acc += awing_elem(inp[i], tgt[i]);
    }

    // wave-64 butterfly reduce
    #pragma unroll
    for (int off = 32; off > 0; off >>= 1)
        acc += __shfl_down(acc, off, 64);

    __shared__ float sacc[NTHREADS / 64];
    const int lane = threadIdx.x & 63;
    const int wid  = threadIdx.x >> 6;
    if (lane == 0) sacc[wid] = acc;
    __syncthreads();
    if (threadIdx.x == 0) {
        float s = 0.0f;
        #pragma unroll
        for (int w = 0; w < NTHREADS / 64; ++w) s += sacc[w];
        partial[blockIdx.x] = s;
    }
}

__global__ __launch_bounds__(NTHREADS) void awing_final_kernel(
    const float* __restrict__ partial, float* __restrict__ out, int nparts)
{
    float acc = 0.0f;
    for (int i = threadIdx.x; i < nparts; i += NTHREADS)
        acc += partial[i];

    #pragma unroll
    for (int off = 32; off > 0; off >>= 1)
        acc += __shfl_down(acc, off, 64);

    __shared__ float sacc[NTHREADS / 64];
    const int lane = threadIdx.x & 63;
    const int wid  = threadIdx.x >> 6;
    if (lane == 0) sacc[wid] = acc;
    __syncthreads();
    if (threadIdx.x == 0) {
        float s = 0.0f;
        #pragma unroll
        for (int w = 0; w < NTHREADS / 64; ++w) s += sacc[w];
        out[0] = s;
    }
}

extern "C" void kernel_launch(void* const* d_in, const int* in_sizes, int n_in,
                              void* d_out, int out_size, void* d_ws, size_t ws_size,
                              hipStream_t stream) {
    const float* inp = (const float*)d_in[0];
    const float* tgt = (const float*)d_in[1];
    float* out       = (float*)d_out;
    float* partial   = (float*)d_ws;   // MAXBLOCKS floats = 8 KB scratch

    const int n = in_sizes[0];

    int nblocks = (n / 4 + NTHREADS - 1) / NTHREADS;
    if (nblocks > MAXBLOCKS) nblocks = MAXBLOCKS;
    if (nblocks < 1) nblocks = 1;

    awing_partial_kernel<<<nblocks, NTHREADS, 0, stream>>>(inp, tgt, partial, n);
    awing_final_kernel<<<1, NTHREADS, 0, stream>>>(partial, out, nblocks);
}

// Round 13
// 145.347 us; speedup vs baseline: 1.5462x; 1.5462x over previous
//
#include <hip/hip_runtime.h>
#include <math.h>

#define NTHREADS 256
#define MAXBLOCKS 2048

// Adaptive Wing loss, fused elementwise + partial reduction.
// THETA=0.5, ALPHA=2.1, W=14, E=1.
//   expo = 2.1 - y
//   p    = 0.5^expo = exp2(-expo)
//   A    = 28*expo*p/(1+p)          [since 0.5^(expo-1) = 2p]
//   loss_large = A*(diff - 0.5) + 14*log1p(p)
//   loss_small = 14*log1p(diff^expo)
// All transcendentals via gfx950 HW instructions (v_exp_f32 / v_log_f32 /
// v_rcp_f32, quarter-rate) instead of software libm (log1pf/log2f/fdiv were
// ~300 issue-cycles per wave-elem -> VALUBusy 92%, 133us).
// log1p(x) = ln2 * v_log(1+x): args are O(0.2-0.5); tiny-x terms contribute
// negligibly to the ~3e7 sum, so the log1p precision trick is not needed.
// diff==0 edge: v_log(0)=-inf -> exp2(-inf)=0 -> log2(1)=0. Correct limit.

#define LN2F 0.69314718056f
#define W_LN2F 9.70406052783923f   // 14*ln2

__device__ __forceinline__ float awing_elem(float xv, float yv) {
    float expo  = 2.1f - yv;
    float p     = __builtin_amdgcn_exp2f(-expo);
    float l2_1p = __builtin_amdgcn_logf(1.0f + p);      // log2(1+p)
    float A     = 28.0f * expo * p * __builtin_amdgcn_rcpf(1.0f + p);
    float diff  = fabsf(yv - xv);
    // diff^expo = exp2(expo * log2(diff))
    float t     = __builtin_amdgcn_exp2f(expo * __builtin_amdgcn_logf(diff));
    float lsml  = W_LN2F * __builtin_amdgcn_logf(1.0f + t);
    float llrg  = fmaf(A, diff - 0.5f, W_LN2F * l2_1p);
    return (diff < 0.5f) ? lsml : llrg;
}

__global__ __launch_bounds__(NTHREADS) void awing_partial_kernel(
    const float* __restrict__ inp, const float* __restrict__ tgt,
    float* __restrict__ partial, int n)
{
    const int tid    = blockIdx.x * blockDim.x + threadIdx.x;
    const int stride = gridDim.x * blockDim.x;
    const int n4     = n >> 2;

    const float4* __restrict__ in4 = (const float4*)inp;
    const float4* __restrict__ tg4 = (const float4*)tgt;

    float acc = 0.0f;
    int i = tid;
    // 2x-unrolled main loop: two coalesced float4 streams in flight
    for (; i + stride < n4; i += 2 * stride) {
        float4 x0 = in4[i];
        float4 y0 = tg4[i];
        float4 x1 = in4[i + stride];
        float4 y1 = tg4[i + stride];
        acc += awing_elem(x0.x, y0.x);
        acc += awing_elem(x0.y, y0.y);
        acc += awing_elem(x0.z, y0.z);
        acc += awing_elem(x0.w, y0.w);
        acc += awing_elem(x1.x, y1.x);
        acc += awing_elem(x1.y, y1.y);
        acc += awing_elem(x1.z, y1.z);
        acc += awing_elem(x1.w, y1.w);
    }
    for (; i < n4; i += stride) {
        float4 x = in4[i];
        float4 y = tg4[i];
        acc += awing_elem(x.x, y.x);
        acc += awing_elem(x.y, y.y);
        acc += awing_elem(x.z, y.z);
        acc += awing_elem(x.w, y.w);
    }
    // scalar tail (n % 4 != 0)
    for (int j = (n4 << 2) + tid; j < n; j += stride) {
        acc += awing_elem(inp[j], tgt[j]);
    }

    // wave-64 butterfly reduce
    #pragma unroll
    for (int off = 32; off > 0; off >>= 1)
        acc += __shfl_down(acc, off, 64);

    __shared__ float sacc[NTHREADS / 64];
    const int lane = threadIdx.x & 63;
    const int wid  = threadIdx.x >> 6;
    if (lane == 0) sacc[wid] = acc;
    __syncthreads();
    if (threadIdx.x == 0) {
        float s = 0.0f;
        #pragma unroll
        for (int w = 0; w < NTHREADS / 64; ++w) s += sacc[w];
        partial[blockIdx.x] = s;
    }
}

__global__ __launch_bounds__(NTHREADS) void awing_final_kernel(
    const float* __restrict__ partial, float* __restrict__ out, int nparts)
{
    float acc = 0.0f;
    for (int i = threadIdx.x; i < nparts; i += NTHREADS)
        acc += partial[i];

    #pragma unroll
    for (int off = 32; off > 0; off >>= 1)
        acc += __shfl_down(acc, off, 64);

    __shared__ float sacc[NTHREADS / 64];
    const int lane = threadIdx.x & 63;
    const int wid  = threadIdx.x >> 6;
    if (lane == 0) sacc[wid] = acc;
    __syncthreads();
    if (threadIdx.x == 0) {
        float s = 0.0f;
        #pragma unroll
        for (int w = 0; w < NTHREADS / 64; ++w) s += sacc[w];
        out[0] = s;
    }
}

extern "C" void kernel_launch(void* const* d_in, const int* in_sizes, int n_in,
                              void* d_out, int out_size, void* d_ws, size_t ws_size,
                              hipStream_t stream) {
    const float* inp = (const float*)d_in[0];
    const float* tgt = (const float*)d_in[1];
    float* out       = (float*)d_out;
    float* partial   = (float*)d_ws;   // MAXBLOCKS floats = 8 KB scratch

    const int n = in_sizes[0];

    int nblocks = (n / 4 + NTHREADS - 1) / NTHREADS;
    if (nblocks > MAXBLOCKS) nblocks = MAXBLOCKS;
    if (nblocks < 1) nblocks = 1;

    awing_partial_kernel<<<nblocks, NTHREADS, 0, stream>>>(inp, tgt, partial, n);
    awing_final_kernel<<<1, NTHREADS, 0, stream>>>(partial, out, nblocks);
}